// Round 1
// baseline (273.546 us; speedup 1.0000x reference)
//
#include <hip/hip_runtime.h>

#define NLAYER 4
#define B_ 128
#define D_ 1024
#define H4_ 4096
#define K_ 2048          // x(1024) ++ h(1024)
#define BK 64
#define NCH 32           // K_/BK
#define OUTSEC 131072    // 128*1024

typedef float f32x4 __attribute__((ext_vector_type(4)));
typedef _Float16 h8 __attribute__((ext_vector_type(8)));
typedef _Float16 h4 __attribute__((ext_vector_type(4)));

// LDS map (bytes)
#define LDS_AH 0         // [2 buf][128 rows][64 cols] fp16 = 2*16384
#define LDS_WH 32768     // [2][16][64] fp16 = 2*2048
#define LDS_WL 36864     // [2][16][64] fp16 = 2*2048
#define LDS_TOT 40960

// 16B global->LDS stage. gsrc is per-lane; lds dest is wave-uniform base,
// HW writes at base + lane*16 (guide m104). Fallback keeps identical layout.
__device__ __forceinline__ void stage16(const void* gsrc, char* lds_uniform, int lane) {
#if __has_builtin(__builtin_amdgcn_global_load_lds)
  __builtin_amdgcn_global_load_lds((const __attribute__((address_space(1))) void*)gsrc,
                                   (__attribute__((address_space(3))) void*)lds_uniform,
                                   16, 0, 0);
#else
  *(h8*)(lds_uniform + lane * 16) = *(const h8*)gsrc;
#endif
}

struct ALF { h8 v[4]; };   // A_lo frags [m*2+ks], always constant-indexed

// -------------------- prep: fp32 -> fp16 hi/lo for x and h0 --------------------
__global__ __launch_bounds__(256)
void prep_kernel(const float* __restrict__ x, const float* __restrict__ h0,
                 _Float16* __restrict__ Ah, _Float16* __restrict__ Al)
{
  int i = (blockIdx.x * 256 + threadIdx.x) * 4;   // 640*256*4 = 655360 exact
  const float* src;
  int dst;
  if (i < 131072) {                 // x -> layer0 A[:, 0:1024]
    int b = i >> 10, k = i & 1023;
    src = x + i;
    dst = b * K_ + k;
  } else {                          // h0[l] -> A_l[:, 1024:2048]
    int j = i - 131072;
    int l = j >> 17, r = j & 131071;
    int b = r >> 10, k = r & 1023;
    src = h0 + j;
    dst = l * (B_ * K_) + b * K_ + D_ + k;
  }
  f32x4 v = *(const f32x4*)src;
  h4 hi, lo;
#pragma unroll
  for (int j2 = 0; j2 < 4; ++j2) {
    _Float16 h = (_Float16)v[j2];
    hi[j2] = h;
    lo[j2] = (_Float16)((v[j2] - (float)h) * 4096.0f);
  }
  *(h4*)(Ah + dst) = hi;
  *(h4*)(Al + dst) = lo;
}

// -------------------- fused layer: GEMM (split-fp16 MFMA) + LSTM cell --------------------
__global__ __launch_bounds__(256)
void lstm_layer(const float* __restrict__ Wih, const float* __restrict__ Whh,
                const float* __restrict__ bih, const float* __restrict__ bhh,
                const float* __restrict__ c0,
                const _Float16* __restrict__ Ah, const _Float16* __restrict__ Al,
                _Float16* __restrict__ AhN, _Float16* __restrict__ AlN,
                float* __restrict__ out, int layer)
{
  __shared__ __align__(16) char smem[LDS_TOT];
  const int tid  = threadIdx.x;
  const int lane = tid & 63;
  const int wid  = tid >> 6;
  const int u0   = blockIdx.x * 4;        // 4 hidden units per WG

  // ---- W staging addressing: LDS row n = du*4+q -> global W row q*1024+u0+du ----
  const int wrow = tid >> 4;              // n 0..15
  const int kq   = tid & 15;              // 16B quad within BK*4B row
  const int wr   = (wrow & 3) * D_ + u0 + (wrow >> 2);
  const float* wih_p = Wih + (size_t)wr * D_ + kq * 4;
  const float* whh_p = Whh + (size_t)wr * D_ + kq * 4;
  const int wbyte = wrow * 128 + ((kq * 8) ^ ((wrow & 7) << 4));   // XOR-swizzled

  // ---- A_hi staging: linear LDS dest, pre-swizzled global source (m173 pattern) ----
  const int R0   = wid * 32 + (lane >> 3);               // R&7 == lane>>3
  const int cswz = ((lane & 7) ^ (lane >> 3)) * 8;       // swizzled 16B chunk, in elems
  const _Float16* ahg = Ah + (size_t)R0 * K_ + cswz;

  // ---- fragment read offsets ----
  const int arow = wid * 32 + (lane & 15);
  const int aswz = (lane & 7) << 4;
  const int wn = lane & 15, wc = lane >> 4;
  const int wswz = (wn & 7) << 4;
  const _Float16* alg = Al + (size_t)arow * K_ + wc * 8;  // A_lo straight from L2

  f32x4 acc_h[2] = {{0.f,0.f,0.f,0.f},{0.f,0.f,0.f,0.f}};
  f32x4 acc_s[2] = {{0.f,0.f,0.f,0.f},{0.f,0.f,0.f,0.f}};

  auto loadW = [&](int t) -> f32x4 {
    const float* p = (t < 16) ? (wih_p + t * BK) : (whh_p + (t - 16) * BK);
    return *(const f32x4*)p;
  };
  auto stageA = [&](int t, int buf) {
    const _Float16* g = ahg + t * BK;
    char* lb = smem + LDS_AH + buf * 16384 + wid * 4096;
    stage16(g,            lb,        lane);
    stage16(g +  8 * K_,  lb + 1024, lane);
    stage16(g + 16 * K_,  lb + 2048, lane);
    stage16(g + 24 * K_,  lb + 3072, lane);
  };
  auto stageW = [&](f32x4 w, int buf) {
    h4 hi, lo;
#pragma unroll
    for (int j = 0; j < 4; ++j) {
      _Float16 h = (_Float16)w[j];
      hi[j] = h;
      lo[j] = (_Float16)((w[j] - (float)h) * 4096.0f);   // scaled: avoids fp16 denormals
    }
    *(h4*)(smem + LDS_WH + buf * 2048 + wbyte) = hi;
    *(h4*)(smem + LDS_WL + buf * 2048 + wbyte) = lo;
  };
  auto loadAL = [&](int t) -> ALF {
    ALF r;
#pragma unroll
    for (int m = 0; m < 2; ++m)
#pragma unroll
      for (int ks = 0; ks < 2; ++ks)
        r.v[m * 2 + ks] = *(const h8*)(alg + (size_t)m * 16 * K_ + t * BK + ks * 32);
    return r;
  };
  auto mfmaChunk = [&](int buf, const ALF& alf) {
    const char* ab  = smem + LDS_AH + buf * 16384;
    const char* whb = smem + LDS_WH + buf * 2048;
    const char* wlb = smem + LDS_WL + buf * 2048;
    h8 a[2][2], wh[2], wl[2];
#pragma unroll
    for (int ks = 0; ks < 2; ++ks) {
      int wo = wn * 128 + ((ks * 64 + wc * 16) ^ wswz);
      wh[ks] = *(const h8*)(whb + wo);
      wl[ks] = *(const h8*)(wlb + wo);
#pragma unroll
      for (int m = 0; m < 2; ++m)
        a[m][ks] = *(const h8*)(ab + (arow + m * 16) * 128 + ((ks * 64 + wc * 16) ^ aswz));
    }
#pragma unroll
    for (int m = 0; m < 2; ++m)
#pragma unroll
      for (int ks = 0; ks < 2; ++ks) {
        acc_h[m] = __builtin_amdgcn_mfma_f32_16x16x32_f16(a[m][ks],        wh[ks], acc_h[m], 0, 0, 0);
        acc_s[m] = __builtin_amdgcn_mfma_f32_16x16x32_f16(alf.v[m*2+ks],   wh[ks], acc_s[m], 0, 0, 0);
        acc_s[m] = __builtin_amdgcn_mfma_f32_16x16x32_f16(a[m][ks],        wl[ks], acc_s[m], 0, 0, 0);
      }
  };

  // ---- prologue ----
  f32x4 w0  = loadW(0);
  f32x4 wnB = loadW(1);    // consumed at even bodies (chunk t+1)
  f32x4 wnA = loadW(2);    // consumed at odd bodies  (chunk t+2)
  ALF alfA = loadAL(0);
  ALF alfB;
  stageA(0, 0);
  stageW(w0, 0);
  __syncthreads();

  // ---- main loop, unrolled x2 so all ring indices are compile-time ----
  for (int t = 0; t < NCH; t += 2) {
    // even chunk t (buf 0)
    stageA(t + 1, 1);
    alfB = loadAL(t + 1);
    mfmaChunk(0, alfA);
    stageW(wnB, 1);
    if (t + 3 < NCH) wnB = loadW(t + 3);
    __syncthreads();
    // odd chunk t+1 (buf 1)
    if (t + 2 < NCH) { stageA(t + 2, 0); alfA = loadAL(t + 2); }
    mfmaChunk(1, alfB);
    if (t + 2 < NCH) stageW(wnA, 0);
    if (t + 4 < NCH) wnA = loadW(t + 4);
    __syncthreads();
  }

  // ---- fused LSTM cell epilogue ----
  float* cb   = (float*)smem;           // overlay: [4 waves][16 n][33] f32 (pad +1)
  float* mycb = cb + wid * 528;
  const float INV = 1.0f / 4096.0f;
#pragma unroll
  for (int m = 0; m < 2; ++m)
#pragma unroll
    for (int j = 0; j < 4; ++j) {
      int r32 = m * 16 + (lane >> 4) * 4 + j;            // verified C layout (m89/m91)
      mycb[(lane & 15) * 33 + r32] = acc_h[m][j] + acc_s[m][j] * INV;
    }
  __syncthreads();

#pragma unroll
  for (int it = 0; it < 2; ++it) {
    int cid = it * 64 + lane;           // 128 cells/wave: 4 du x 32 rows
    int du = cid >> 5, r32 = cid & 31;
    int row = wid * 32 + r32;
    int u = u0 + du;
    float gi = mycb[(du * 4 + 0) * 33 + r32] + bih[u]           + bhh[u];
    float gf = mycb[(du * 4 + 1) * 33 + r32] + bih[D_ + u]      + bhh[D_ + u];
    float gg = mycb[(du * 4 + 2) * 33 + r32] + bih[2 * D_ + u]  + bhh[2 * D_ + u];
    float go = mycb[(du * 4 + 3) * 33 + r32] + bih[3 * D_ + u]  + bhh[3 * D_ + u];
    float iv = 1.0f / (1.0f + __expf(-gi));
    float fv = 1.0f / (1.0f + __expf(-gf));
    float gv = tanhf(gg);
    float ov = 1.0f / (1.0f + __expf(-go));
    float c0v = c0[row * D_ + u];
    float c1  = fv * c0v + iv * gv;
    float h1v = ov * tanhf(c1);
    out[(5 + layer) * OUTSEC + row * D_ + u] = c1;    // c stack
    out[(1 + layer) * OUTSEC + row * D_ + u] = h1v;   // h stack
    if (layer == 3) {
      out[row * D_ + u] = h1v;                        // final inp
    } else {
      _Float16 hh = (_Float16)h1v;
      AhN[row * K_ + u] = hh;                         // feeds next layer [:, 0:1024]
      AlN[row * K_ + u] = (_Float16)((h1v - (float)hh) * 4096.0f);
    }
  }
}

// -------------------- host launch --------------------
extern "C" void kernel_launch(void* const* d_in, const int* in_sizes, int n_in,
                              void* d_out, int out_size, void* d_ws, size_t ws_size,
                              hipStream_t stream)
{
  const float* x   = (const float*)d_in[0];
  const float* h0  = (const float*)d_in[1];
  const float* c0  = (const float*)d_in[2];
  const float* Wih = (const float*)d_in[3];
  const float* Whh = (const float*)d_in[4];
  const float* bih = (const float*)d_in[5];
  const float* bhh = (const float*)d_in[6];
  float* out = (float*)d_out;

  _Float16* Ah = (_Float16*)d_ws;          // [4][128][2048] hi
  _Float16* Al = Ah + 4 * B_ * K_;         // [4][128][2048] lo  (ws use: 4 MB)

  prep_kernel<<<640, 256, 0, stream>>>(x, h0, Ah, Al);
  for (int l = 0; l < NLAYER; ++l) {
    lstm_layer<<<256, 256, 0, stream>>>(
        Wih + (size_t)l * H4_ * D_, Whh + (size_t)l * H4_ * D_,
        bih + l * H4_, bhh + l * H4_,
        c0 + l * (B_ * D_),
        Ah + l * (B_ * K_), Al + l * (B_ * K_),
        (l < 3) ? Ah + (l + 1) * (B_ * K_) : (_Float16*)nullptr,
        (l < 3) ? Al + (l + 1) * (B_ * K_) : (_Float16*)nullptr,
        out, l);
  }
}